// Round 1
// baseline (311.190 us; speedup 1.0000x reference)
//
#include <hip/hip_runtime.h>

#define TILE_N 64

// Kernel A: Wr[k][o][c] = W[o, c*25 + k]   (W is [64][800], layout col = c*K+k)
__global__ void prep_w(const float* __restrict__ W, float* __restrict__ Wr) {
    int i = blockIdx.x * blockDim.x + threadIdx.x;  // over 25*64*32 = 51200
    if (i >= 25 * 64 * 32) return;
    int c = i & 31;
    int o = (i >> 5) & 63;
    int k = i >> 11;
    Wr[i] = W[o * 800 + c * 25 + k];
}

// Kernel B: transpose x (B,C,N) -> xt (B,N,C) so gathers are contiguous 128B
__global__ void transpose_x(const float* __restrict__ x, float* __restrict__ xt, int N) {
    __shared__ float t[32][65];
    int b = blockIdx.y;
    int n0 = blockIdx.x * 64;
    int tid = threadIdx.x;
#pragma unroll
    for (int i = 0; i < 8; ++i) {
        int e = tid + 256 * i;
        int c = e >> 6, nl = e & 63;
        int n = n0 + nl;
        float v = 0.f;
        if (n < N) v = x[(size_t)(b * 32 + c) * N + n];
        t[c][nl] = v;
    }
    __syncthreads();
#pragma unroll
    for (int i = 0; i < 8; ++i) {
        int e = tid + 256 * i;
        int nl = e >> 5, c = e & 31;
        int n = n0 + nl;
        if (n < N) xt[((size_t)b * N + n) * 32 + c] = t[c][nl];
    }
}

// Kernel C: fused gather + einsum + GEMM + bias
//  out[b,o,n] = sum_{c,k} ( sum_t xt[b, idx[n,k,t], c] * w[n,k,t] ) * Wr[k,o,c] + bias[o]
__global__ __launch_bounds__(256) void fused_main(
    const float* __restrict__ xt,    // [2][N][32]
    const float* __restrict__ Wr,    // [25][64][32]
    const float* __restrict__ bias,  // [64]
    const int*   __restrict__ nidx,  // [N][25][3]
    const float* __restrict__ nw,    // [N][25][3]
    float* __restrict__ out,         // [2][64][N]
    int N)
{
    // s tile: stride 36 floats (16B-aligned rows, conflict-free b128 reads)
    __shared__ float s_lds[2 * 64 * 36];
    __shared__ int   idxs[64][3];
    __shared__ float wts[64][3];

    const int tid = threadIdx.x;
    const int n0 = blockIdx.x * TILE_N;

    float acc[2][16];
#pragma unroll
    for (int b = 0; b < 2; ++b)
#pragma unroll
        for (int i = 0; i < 16; ++i) acc[b][i] = 0.f;

    const int c_lane = tid & 31;
    const int grp    = tid >> 5;   // 0..7 (32-lane groups)
    const int nl_c   = tid & 63;   // n within tile for phase C
    const int g      = tid >> 6;   // 0..3 (wave id)

    for (int k = 0; k < 25; ++k) {
        // ---- phase A: stage this k's indices/weights for the 64 n's ----
        if (tid < 192) {
            int nl = tid / 3, t = tid - nl * 3;
            int n = n0 + nl;
            int j = 0; float w = 0.f;
            if (n < N) {
                size_t base = ((size_t)n * 25 + k) * 3 + t;
                j = nidx[base];
                w = nw[base];
            }
            idxs[nl][t] = j;
            wts[nl][t]  = w;
        }
        __syncthreads();

        // ---- phase B: s[b,nl,c] for 128 (b,nl) combos; 32-lane group per combo ----
#pragma unroll
        for (int m = 0; m < 16; ++m) {
            int combo = grp * 16 + m;          // 0..127
            int b  = combo >> 6;
            int nl = combo & 63;
            const float* xb = xt + (size_t)b * N * 32;
            int j0 = idxs[nl][0], j1 = idxs[nl][1], j2 = idxs[nl][2];
            float s = xb[(size_t)j0 * 32 + c_lane] * wts[nl][0]
                    + xb[(size_t)j1 * 32 + c_lane] * wts[nl][1]
                    + xb[(size_t)j2 * 32 + c_lane] * wts[nl][2];
            s_lds[combo * 36 + c_lane] = s;
        }
        __syncthreads();

        // ---- phase C: register-blocked accumulate against Wr[k] ----
        float sreg[2][32];
#pragma unroll
        for (int b = 0; b < 2; ++b)
#pragma unroll
            for (int c = 0; c < 32; ++c)
                sreg[b][c] = s_lds[(b * 64 + nl_c) * 36 + c];

        const float* wk = Wr + k * 64 * 32;
#pragma unroll
        for (int oi = 0; oi < 16; ++oi) {
            int o = __builtin_amdgcn_readfirstlane(g * 16 + oi);  // wave-uniform -> s_load
            const float* wrow = wk + o * 32;
            float a0 = acc[0][oi], a1 = acc[1][oi];
#pragma unroll
            for (int c = 0; c < 32; ++c) {
                float wv = wrow[c];
                a0 += sreg[0][c] * wv;
                a1 += sreg[1][c] * wv;
            }
            acc[0][oi] = a0; acc[1][oi] = a1;
        }
        __syncthreads();  // protect idxs/wts/s_lds before next iteration
    }

    // ---- epilogue: bias + coalesced store ----
    int n = n0 + nl_c;
    if (n < N) {
#pragma unroll
        for (int oi = 0; oi < 16; ++oi) {
            int o = g * 16 + oi;
            float bv = bias[o];
            out[(size_t)(0 * 64 + o) * N + n] = acc[0][oi] + bv;
            out[(size_t)(1 * 64 + o) * N + n] = acc[1][oi] + bv;
        }
    }
}

extern "C" void kernel_launch(void* const* d_in, const int* in_sizes, int n_in,
                              void* d_out, int out_size, void* d_ws, size_t ws_size,
                              hipStream_t stream) {
    const float* x    = (const float*)d_in[0];   // (2,32,N)
    const float* nw   = (const float*)d_in[1];   // (N,25,3)
    const float* W    = (const float*)d_in[2];   // (64,800)
    const float* bias = (const float*)d_in[3];   // (64,)
    const int*   nidx = (const int*)d_in[4];     // (N,25,3)
    float* out = (float*)d_out;

    int N = in_sizes[0] / 64;  // B*C = 64

    float* xt = (float*)d_ws;                     // 2*N*32 floats = ~10.5 MB
    float* Wr = xt + (size_t)2 * N * 32;          // 51200 floats

    prep_w<<<(25 * 64 * 32 + 255) / 256, 256, 0, stream>>>(W, Wr);

    dim3 tg((N + 63) / 64, 2);
    transpose_x<<<tg, 256, 0, stream>>>(x, xt, N);

    fused_main<<<(N + 63) / 64, 256, 0, stream>>>(xt, Wr, bias, nidx, nw, out, N);
}

// Round 2
// 79.459 us; speedup vs baseline: 3.9164x; 3.9164x over previous
//
#include <hip/hip_runtime.h>
#include <hip/hip_bf16.h>

typedef __attribute__((ext_vector_type(8))) short bf16x8;
typedef __attribute__((ext_vector_type(4))) float f32x4;

static __device__ __forceinline__ float bflo(unsigned int u) {
    return __uint_as_float(u << 16);
}
static __device__ __forceinline__ float bfhi(unsigned int u) {
    return __uint_as_float(u & 0xffff0000u);
}
static __device__ __forceinline__ unsigned int packbf(float a, float b) {
    __hip_bfloat16 ha = __float2bfloat16(a);
    __hip_bfloat16 hb = __float2bfloat16(b);
    unsigned short ua = *reinterpret_cast<unsigned short*>(&ha);
    unsigned short ub = *reinterpret_cast<unsigned short*>(&hb);
    return (unsigned int)ua | ((unsigned int)ub << 16);
}

// Kernel A: Wrb[k][o][c] = bf16(W[o, c*25 + k])
__global__ void prep_w(const float* __restrict__ W, unsigned short* __restrict__ Wrb) {
    int i = blockIdx.x * 256 + threadIdx.x;  // 25*64*32 = 51200
    if (i >= 25 * 64 * 32) return;
    int c = i & 31;
    int o = (i >> 5) & 63;
    int k = i >> 11;
    __hip_bfloat16 h = __float2bfloat16(W[o * 800 + c * 25 + k]);
    Wrb[i] = *reinterpret_cast<unsigned short*>(&h);
}

// Kernel B: transpose x (B,C,N) fp32 -> xtb (B,N,32) bf16 (64B per (b,n), gather-friendly)
__global__ __launch_bounds__(256) void transpose_x(const float* __restrict__ x,
                                                   unsigned short* __restrict__ xtb, int N) {
    __shared__ float t[32][65];
    int b = blockIdx.y;
    int n0 = blockIdx.x * 64;
    int tid = threadIdx.x;
#pragma unroll
    for (int i = 0; i < 8; ++i) {
        int e = tid + 256 * i;
        int c = e >> 6, nl = e & 63;
        int n = n0 + nl;
        t[c][nl] = (n < N) ? x[(size_t)(b * 32 + c) * N + n] : 0.f;
    }
    __syncthreads();
    int nl = tid >> 2, cg = tid & 3;
    int n = n0 + nl;
    if (n < N) {
        uint4 p;
        p.x = packbf(t[cg * 8 + 0][nl], t[cg * 8 + 1][nl]);
        p.y = packbf(t[cg * 8 + 2][nl], t[cg * 8 + 3][nl]);
        p.z = packbf(t[cg * 8 + 4][nl], t[cg * 8 + 5][nl]);
        p.w = packbf(t[cg * 8 + 6][nl], t[cg * 8 + 7][nl]);
        *reinterpret_cast<uint4*>(xtb + ((size_t)(b * N + n) * 32 + cg * 8)) = p;
    }
}

// Kernel C: fused gather + einsum + MFMA GEMM + bias
// out[b,o,n] = sum_{k,c} s[b,n,k,c] * Wrb[k,o,c] + bias[o],
// s[b,n,k,c] = sum_t xtb[b, idx[n,k,t], c] * w[n,k,t]
__global__ __launch_bounds__(256, 5) void fused_main(
    const unsigned short* __restrict__ xtb,   // [2][N][32] bf16
    const unsigned short* __restrict__ Wrb,   // [25][64][32] bf16
    const float* __restrict__ bias,           // [64]
    const int* __restrict__ nidx,             // [N][25][3]
    const float* __restrict__ nw,             // [N][25][3]
    float* __restrict__ out,                  // [2][64][N]
    int N)
{
    __shared__ int2 idxw[25 * 32 * 3];                       // (j, w_bits) pairs
    __shared__ __align__(16) unsigned char sA[64 * 64];      // swizzled [row=b*32+nl][c] bf16
    __shared__ __align__(16) unsigned char sB[64 * 64];      // swizzled [o][c] bf16

    const int tid = threadIdx.x;
    const int n0 = blockIdx.x * 32;

    // ---- preload all 25 k-slices of indices+weights (fully coalesced) ----
#pragma unroll
    for (int it = 0; it < 10; ++it) {
        int e = tid + 256 * it;
        if (e < 2400) {
            int nl = e / 75;
            int rem = e - nl * 75;
            int n = n0 + nl;
            int j = 0, wbits = 0;
            if (n < N) {
                j = nidx[(size_t)n0 * 75 + e];
                wbits = __float_as_int(nw[(size_t)n0 * 75 + e]);
            }
            int kk = rem / 3, t = rem - kk * 3;
            idxw[(kk * 32 + nl) * 3 + t] = make_int2(j, wbits);
        }
    }
    __syncthreads();

    const int grp = tid >> 3, l8 = tid & 7;   // 32 groups x 8 lanes
    const int row0 = grp * 2;                 // each group owns rows row0, row0+1
    const int b0 = row0 >> 5;                 // same b for both rows (row0 even)
    const int nl0 = row0 & 31;

    uint4 rB;
    uint2 rg[2][3];
    float rw[2][3];

    auto issue_tile = [&](int kk_) {
        rB = *reinterpret_cast<const uint4*>(Wrb + kk_ * 2048 + tid * 8);
#pragma unroll
        for (int r = 0; r < 2; ++r) {
            const int2* ip = &idxw[((kk_ * 32) + nl0 + r) * 3];
#pragma unroll
            for (int t = 0; t < 3; ++t) {
                int2 jw = ip[t];
                rw[r][t] = __int_as_float(jw.y);
                rg[r][t] = *reinterpret_cast<const uint2*>(
                    xtb + ((size_t)(b0 * N + jw.x) * 32 + l8 * 4));
            }
        }
    };

    f32x4 acc[4];
#pragma unroll
    for (int ot = 0; ot < 4; ++ot) acc[ot] = (f32x4){0.f, 0.f, 0.f, 0.f};

    issue_tile(0);

    for (int kk = 0; kk < 25; ++kk) {
        // ---- write staged B slice (swizzled) ----
        {
            int o = tid >> 2, cg = tid & 3;
            int ad = (o * 64 + cg * 16) ^ ((o & 7) << 4);
            *reinterpret_cast<uint4*>(sB + ad) = rB;
        }
        // ---- weighted-gather -> bf16 -> LDS A slice (swizzled) ----
#pragma unroll
        for (int r = 0; r < 2; ++r) {
            int row = row0 + r;
            float w0 = rw[r][0], w1 = rw[r][1], w2 = rw[r][2];
            uint2 v0 = rg[r][0], v1 = rg[r][1], v2 = rg[r][2];
            float a0 = bflo(v0.x) * w0 + bflo(v1.x) * w1 + bflo(v2.x) * w2;
            float a1 = bfhi(v0.x) * w0 + bfhi(v1.x) * w1 + bfhi(v2.x) * w2;
            float a2 = bflo(v0.y) * w0 + bflo(v1.y) * w1 + bflo(v2.y) * w2;
            float a3 = bfhi(v0.y) * w0 + bfhi(v1.y) * w1 + bfhi(v2.y) * w2;
            uint2 p;
            p.x = packbf(a0, a1);
            p.y = packbf(a2, a3);
            int ad = (row * 64 + l8 * 8) ^ ((row & 7) << 4);
            *reinterpret_cast<uint2*>(sA + ad) = p;
        }
        // issue next tile's loads early (overlap with MFMA below)
        if (kk < 24) issue_tile(kk + 1);
        __syncthreads();

        // ---- MFMA phase: 4 waves, each owns a 16-row m-tile, 4 o-tiles ----
        {
            const int l = tid & 63, wv = tid >> 6;
            const int g = l >> 4, c16 = l & 15;
            int arow = 16 * wv + c16;
            bf16x8 af = *reinterpret_cast<const bf16x8*>(
                sA + ((arow * 64 + g * 16) ^ ((arow & 7) << 4)));
#pragma unroll
            for (int ot = 0; ot < 4; ++ot) {
                int o = ot * 16 + c16;
                bf16x8 bfrag = *reinterpret_cast<const bf16x8*>(
                    sB + ((o * 64 + g * 16) ^ ((o & 7) << 4)));
                acc[ot] = __builtin_amdgcn_mfma_f32_16x16x32_bf16(af, bfrag, acc[ot], 0, 0, 0);
            }
        }
        __syncthreads();
    }

    // ---- epilogue: bias + store (D: col=lane&15, row=4*(lane>>4)+i) ----
    const int l = tid & 63, wv = tid >> 6;
    const int g = l >> 4, c16 = l & 15;
#pragma unroll
    for (int ot = 0; ot < 4; ++ot) {
        int o = ot * 16 + c16;
        float bv = bias[o];
#pragma unroll
        for (int i = 0; i < 4; ++i) {
            int mrow = 16 * wv + 4 * g + i;
            int b = mrow >> 5, nl = mrow & 31;
            int n = n0 + nl;
            if (n < N) out[(size_t)(b * 64 + o) * N + n] = acc[ot][i] + bv;
        }
    }
}

extern "C" void kernel_launch(void* const* d_in, const int* in_sizes, int n_in,
                              void* d_out, int out_size, void* d_ws, size_t ws_size,
                              hipStream_t stream) {
    const float* x    = (const float*)d_in[0];   // (2,32,N)
    const float* nw   = (const float*)d_in[1];   // (N,25,3)
    const float* W    = (const float*)d_in[2];   // (64,800)
    const float* bias = (const float*)d_in[3];   // (64,)
    const int*   nidx = (const int*)d_in[4];     // (N,25,3)
    float* out = (float*)d_out;

    int N = in_sizes[0] / 64;  // B*C = 64

    unsigned short* xtb = (unsigned short*)d_ws;          // 2*N*32 bf16
    unsigned short* Wrb = xtb + (size_t)2 * N * 32;       // 51200 bf16

    prep_w<<<(25 * 64 * 32 + 255) / 256, 256, 0, stream>>>(W, Wrb);

    dim3 tg((N + 63) / 64, 2);
    transpose_x<<<tg, 256, 0, stream>>>(x, xtb, N);

    fused_main<<<(N + 31) / 32, 256, 0, stream>>>(xtb, Wrb, bias, nidx, nw, out, N);
}